// Round 11
// baseline (106.365 us; speedup 1.0000x reference)
//
#include <hip/hip_runtime.h>

#define NB 8192
#define ND 128
#define MARGINF 0.3f
#define FLTMAX 3.402823466e+38f
#define A_TILES 8             // scan cap: 8 x 16 = 128 cols
#define FIN_BLOCKS 1024       // 8-row stripes
#define DIAG_COL 0xFFFFFFFEULL

// ws layout (bytes):
//   [0]     float dapw[8192]     (always written by scan)
//   [32768] u64   idxval[8192]   (always written: key or ~0; finish fills the rest)

__device__ __forceinline__ float dot4(float4 x, float4 y) {
    return x.x * y.x + x.y * y.y + x.z * y.z + x.w * y.w;
}

// Butterfly sum within each 32-lane half.
__device__ __forceinline__ float half_reduce(float v) {
    v += __shfl_xor(v, 1, 64);
    v += __shfl_xor(v, 2, 64);
    v += __shfl_xor(v, 4, 64);
    v += __shfl_xor(v, 8, 64);
    v += __shfl_xor(v, 16, 64);
    return v;
}

// Lane owning local column c: col(L) = 2*(L&31) + (L>>5).
__device__ __forceinline__ int owner(int c) {
    return (c & 1) ? 32 + (c >> 1) : (c >> 1);
}

__device__ __forceinline__ int first_col_from_mask(unsigned long long mask) {
    const unsigned int lo = (unsigned int)mask;          // even local cols
    const unsigned int hi = (unsigned int)(mask >> 32);  // odd local cols
    const int ce = lo ? 2 * (__ffs(lo) - 1)     : 0x7fffffff;
    const int co = hi ? 2 * (__ffs(hi) - 1) + 1 : 0x7fffffff;
    return ce < co ? ce : co;
}

// Phase A: one row per wave, scan cols [0,128) in 16-col mini-tiles, early exit.
// Dense per-row outputs -> no init kernel, no atomics, no worklist.
__global__ __launch_bounds__(256) void triplet_scan(const float* __restrict__ a,
                                                    const float* __restrict__ p,
                                                    const float* __restrict__ n,
                                                    float* __restrict__ dapw,
                                                    unsigned long long* __restrict__ idxval) {
    const int tid  = threadIdx.x;
    const int wave = tid >> 6;
    const int lane = tid & 63;
    const int q    = lane & 31;
    const int h    = lane >> 5;
    const int row  = blockIdx.x * 4 + wave;

    const float4 a4 = *(const float4*)(a + (size_t)row * ND + q * 4);
    const float4 p4 = *(const float4*)(p + (size_t)row * ND + q * 4);
    const float dist_ap = half_reduce(dot4(a4, p4));
    const float thresh  = dist_ap + MARGINF;

    unsigned long long result = ~0ULL;        // unresolved sentinel
    for (int t = 0; t < A_TILES; ++t) {
        float myval = FLTMAX;
        #pragma unroll
        for (int k = 0; k < 8; ++k) {
            const int col = t * 16 + 2 * k + h;
            const float4 nv = *(const float4*)(n + (size_t)col * ND + q * 4);
            const float v = half_reduce(dot4(a4, nv));
            if (q == k) myval = v;
        }
        const unsigned long long mask = __ballot(myval < thresh);
        if (mask) {  // wave-uniform: first tile with a hit; min col inside is exact
            const int c = first_col_from_mask(mask);
            const float dist_an = __shfl(myval, owner(c), 64);
            result = ((unsigned long long)(t * 16 + c) << 32)
                   | (unsigned long long)__float_as_uint(dist_an);
            break;
        }
    }
    if (lane == 0) {
        dapw[row]   = dist_ap;
        idxval[row] = result;
    }
}

// Phase B: block owns 8 rows; for unresolved ones, 4 waves sweep all 128 chunks
// (wave w -> chunks w, w+4, ...; ascending => per-wave early break is exact).
// Diagonal folded in as sentinel-col key. Plain store (exclusive row ownership).
__global__ __launch_bounds__(256) void triplet_finish(const float* __restrict__ a,
                                                      const float* __restrict__ n,
                                                      const float* __restrict__ dapw,
                                                      unsigned long long* __restrict__ idxval) {
    __shared__ unsigned long long s_keys[8];
    __shared__ unsigned long long s_best[4];
    const int tid  = threadIdx.x;
    const int wave = tid >> 6;
    const int lane = tid & 63;
    const int q    = lane & 31;
    const int h    = lane >> 5;
    const int base_row = blockIdx.x * 8;

    if (tid < 8) s_keys[tid] = idxval[base_row + tid];
    __syncthreads();

    for (int i = 0; i < 8; ++i) {
        if (s_keys[i] != ~0ULL) continue;     // resolved (block-uniform via LDS)
        const int r  = base_row + i;
        const float th = dapw[r] + MARGINF;
        const float4 a4 = *(const float4*)(a + (size_t)r * ND + q * 4);
        const int dchunk = r >> 6;

        unsigned long long wkey = ~0ULL;
        for (int ci = 0; ci < 32; ++ci) {
            const int chunk = ci * 4 + wave;  // ascending per wave
            const int tb = chunk << 6;
            float myval = FLTMAX;
            #pragma unroll
            for (int k = 0; k < 32; ++k) {
                const int col = tb + 2 * k + h;
                const float4 nv = *(const float4*)(n + (size_t)col * ND + q * 4);
                const float v = half_reduce(dot4(a4, nv));   // bit-identical to scan
                if (q == k) myval = v;
            }
            if (chunk == dchunk) {            // diag candidate (loses to any hit)
                const float dv = __shfl(myval, owner(r - tb), 64);
                if (lane == 0) {
                    const unsigned long long dkey =
                        (DIAG_COL << 32) | (unsigned long long)__float_as_uint(dv);
                    wkey = dkey < wkey ? dkey : wkey;
                }
            }
            const unsigned long long mask = __ballot(myval < th);
            if (mask) {                       // wave-uniform
                const int c = first_col_from_mask(mask);
                const float fv = __shfl(myval, owner(c), 64);
                if (lane == 0) {
                    const unsigned long long key =
                        ((unsigned long long)(tb + c) << 32)
                        | (unsigned long long)__float_as_uint(fv);
                    wkey = key < wkey ? key : wkey;
                }
                break;                        // later chunks = higher cols
            }
        }
        if (lane == 0) s_best[wave] = wkey;
        __syncthreads();
        if (tid == 0) {
            unsigned long long best = s_best[0];
            if (s_best[1] < best) best = s_best[1];
            if (s_best[2] < best) best = s_best[2];
            if (s_best[3] < best) best = s_best[3];
            idxval[r] = best;                 // never ~0: diag always present if no hit
        }
        __syncthreads();                      // s_best reusable next row
    }
}

// Finale: 1 block, fixed-order deterministic sum of all 8192 losses.
__global__ __launch_bounds__(256) void finale(const float* __restrict__ dapw,
                                              const unsigned long long* __restrict__ idxval,
                                              float* __restrict__ out) {
    __shared__ double s[256];
    const int tid = threadIdx.x;
    double sum = 0.0;
    #pragma unroll
    for (int i = 0; i < NB / 256; ++i) {      // 32 iters, fixed order
        const int w = i * 256 + tid;
        const float an_v = __uint_as_float((unsigned int)idxval[w]);
        const float l = an_v - dapw[w] + MARGINF;
        if (l > 0.f) sum += (double)l;
    }
    s[tid] = sum;
    __syncthreads();
    #pragma unroll
    for (int off = 128; off; off >>= 1) {
        if (tid < off) s[tid] += s[tid + off];
        __syncthreads();
    }
    if (tid == 0) out[0] = (float)(s[0] / (double)NB);
}

extern "C" void kernel_launch(void* const* d_in, const int* in_sizes, int n_in,
                              void* d_out, int out_size, void* d_ws, size_t ws_size,
                              hipStream_t stream) {
    const float* a = (const float*)d_in[0];
    const float* p = (const float*)d_in[1];
    const float* n = (const float*)d_in[2];
    float* out = (float*)d_out;
    char*  ws  = (char*)d_ws;
    float*              dapw   = (float*)ws;
    unsigned long long* idxval = (unsigned long long*)(ws + 32768);

    triplet_scan  <<<NB / 4, 256, 0, stream>>>(a, p, n, dapw, idxval);
    triplet_finish<<<FIN_BLOCKS, 256, 0, stream>>>(a, n, dapw, idxval);
    finale        <<<1, 256, 0, stream>>>(dapw, idxval, out);
}

// Round 12
// 41.465 us; speedup vs baseline: 2.5652x; 2.5652x over previous
//
#include <hip/hip_runtime.h>

#define NB 8192
#define ND 128
#define MARGINF 0.3f
#define FLTMAX 3.402823466e+38f
#define A_TILES 8             // scan cap: 8 x 16 = 128 cols
#define DIAG_COL 0xFFFFFFFEULL

// ws layout (bytes):
//   [0]      float dapw[8192]     dense, written every call
//   [32768]  u64   idxval[8192]   dense: resolved key or ~0; finish atomicMins
//   [98304]  int   list[8192]     row if unresolved else -1
// total 128 KB

__device__ __forceinline__ float dot4(float4 x, float4 y) {
    return x.x * y.x + x.y * y.y + x.z * y.z + x.w * y.w;
}

// Butterfly sum within each 32-lane half.
__device__ __forceinline__ float half_reduce(float v) {
    v += __shfl_xor(v, 1, 64);
    v += __shfl_xor(v, 2, 64);
    v += __shfl_xor(v, 4, 64);
    v += __shfl_xor(v, 8, 64);
    v += __shfl_xor(v, 16, 64);
    return v;
}

// Lane owning local column c: col(L) = 2*(L&31) + (L>>5).
__device__ __forceinline__ int owner(int c) {
    return (c & 1) ? 32 + (c >> 1) : (c >> 1);
}

__device__ __forceinline__ int first_col_from_mask(unsigned long long mask) {
    const unsigned int lo = (unsigned int)mask;          // even local cols
    const unsigned int hi = (unsigned int)(mask >> 32);  // odd local cols
    const int ce = lo ? 2 * (__ffs(lo) - 1)     : 0x7fffffff;
    const int co = hi ? 2 * (__ffs(hi) - 1) + 1 : 0x7fffffff;
    return ce < co ? ce : co;
}

// Phase A: one row per wave, scan cols [0,128) in 16-col mini-tiles, early exit.
// Dense outputs only -> no init node, no global atomics.
__global__ __launch_bounds__(256) void triplet_scan(const float* __restrict__ a,
                                                    const float* __restrict__ p,
                                                    const float* __restrict__ n,
                                                    float* __restrict__ dapw,
                                                    unsigned long long* __restrict__ idxval,
                                                    int* __restrict__ list) {
    const int tid  = threadIdx.x;
    const int wave = tid >> 6;
    const int lane = tid & 63;
    const int q    = lane & 31;
    const int h    = lane >> 5;
    const int row  = blockIdx.x * 4 + wave;

    const float4 a4 = *(const float4*)(a + (size_t)row * ND + q * 4);
    const float4 p4 = *(const float4*)(p + (size_t)row * ND + q * 4);
    const float dist_ap = half_reduce(dot4(a4, p4));
    const float thresh  = dist_ap + MARGINF;

    unsigned long long result = ~0ULL;        // unresolved sentinel
    for (int t = 0; t < A_TILES; ++t) {
        float myval = FLTMAX;
        #pragma unroll
        for (int k = 0; k < 8; ++k) {
            const int col = t * 16 + 2 * k + h;
            const float4 nv = *(const float4*)(n + (size_t)col * ND + q * 4);
            const float v = half_reduce(dot4(a4, nv));
            if (q == k) myval = v;
        }
        const unsigned long long mask = __ballot(myval < thresh);
        if (mask) {  // wave-uniform: first tile with a hit; min col inside is exact
            const int c = first_col_from_mask(mask);
            const float dist_an = __shfl(myval, owner(c), 64);
            result = ((unsigned long long)(t * 16 + c) << 32)
                   | (unsigned long long)__float_as_uint(dist_an);
            break;
        }
    }
    if (lane == 0) {
        dapw[row]   = dist_ap;
        idxval[row] = result;
        list[row]   = (result == ~0ULL) ? row : -1;
    }
}

// Phase B: block (rg, cg) = (blockIdx>>7, blockIdx&127). Compact the rg-slice's
// unresolved rows in LDS, then each wave computes one (row, chunk cg) tile and
// atomicMins the packed key. 128 blocks per row -> perfectly spread.
__global__ __launch_bounds__(256) void triplet_finish(const float* __restrict__ a,
                                                      const float* __restrict__ n,
                                                      const float* __restrict__ dapw,
                                                      const int* __restrict__ list,
                                                      unsigned long long* __restrict__ idxval) {
    __shared__ int s_rows[1024];
    __shared__ int s_cnt;
    const int tid  = threadIdx.x;
    const int wave = tid >> 6;
    const int lane = tid & 63;
    const int q    = lane & 31;
    const int h    = lane >> 5;
    const int cg   = blockIdx.x & 127;        // chunk index [0,128)
    const int rg   = blockIdx.x >> 7;         // row-group [0,8)
    const int tb   = cg << 6;                 // chunk base column

    if (tid == 0) s_cnt = 0;
    __syncthreads();
    #pragma unroll
    for (int i = 0; i < 4; ++i) {             // 1024 ints, coalesced
        const int v = list[rg * 1024 + i * 256 + tid];
        if (v >= 0) s_rows[atomicAdd(&s_cnt, 1)] = v;   // LDS atomic; order moot
    }
    __syncthreads();
    const int cnt = s_cnt;

    for (int t = wave; t < cnt; t += 4) {
        const int r  = s_rows[t];
        const float th = dapw[r] + MARGINF;
        const float4 a4 = *(const float4*)(a + (size_t)r * ND + q * 4);

        float myval = FLTMAX;
        #pragma unroll
        for (int k = 0; k < 32; ++k) {
            const int col = tb + 2 * k + h;
            const float4 nv = *(const float4*)(n + (size_t)col * ND + q * 4);
            const float v = half_reduce(dot4(a4, nv));   // bit-identical to scan
            if (q == k) myval = v;
        }
        if ((r >> 6) == cg) {                 // diag candidate (loses to any hit)
            const float dv = __shfl(myval, owner(r - tb), 64);
            if (lane == 0) {
                const unsigned long long dkey =
                    (DIAG_COL << 32) | (unsigned long long)__float_as_uint(dv);
                atomicMin(&idxval[r], dkey);
            }
        }
        const unsigned long long mask = __ballot(myval < th);
        if (mask) {                           // wave-uniform
            const int c = first_col_from_mask(mask);
            const float fv = __shfl(myval, owner(c), 64);
            if (lane == 0) {
                const unsigned long long key =
                    ((unsigned long long)(tb + c) << 32)
                    | (unsigned long long)__float_as_uint(fv);
                atomicMin(&idxval[r], key);   // min col wins; order-independent
            }
        }
    }
}

// Finale: 1 block, fixed-order deterministic sum of all 8192 losses.
__global__ __launch_bounds__(256) void finale(const float* __restrict__ dapw,
                                              const unsigned long long* __restrict__ idxval,
                                              float* __restrict__ out) {
    __shared__ double s[256];
    const int tid = threadIdx.x;
    double sum = 0.0;
    #pragma unroll
    for (int i = 0; i < NB / 256; ++i) {      // 32 iters, fixed order
        const int w = i * 256 + tid;
        const float an_v = __uint_as_float((unsigned int)idxval[w]);
        const float l = an_v - dapw[w] + MARGINF;
        if (l > 0.f) sum += (double)l;
    }
    s[tid] = sum;
    __syncthreads();
    #pragma unroll
    for (int off = 128; off; off >>= 1) {
        if (tid < off) s[tid] += s[tid + off];
        __syncthreads();
    }
    if (tid == 0) out[0] = (float)(s[0] / (double)NB);
}

extern "C" void kernel_launch(void* const* d_in, const int* in_sizes, int n_in,
                              void* d_out, int out_size, void* d_ws, size_t ws_size,
                              hipStream_t stream) {
    const float* a = (const float*)d_in[0];
    const float* p = (const float*)d_in[1];
    const float* n = (const float*)d_in[2];
    float* out = (float*)d_out;
    char*  ws  = (char*)d_ws;
    float*              dapw   = (float*)ws;
    unsigned long long* idxval = (unsigned long long*)(ws + 32768);
    int*                list   = (int*)(ws + 98304);

    triplet_scan  <<<NB / 4, 256, 0, stream>>>(a, p, n, dapw, idxval, list);
    triplet_finish<<<1024, 256, 0, stream>>>(a, n, dapw, list, idxval);
    finale        <<<1, 256, 0, stream>>>(dapw, idxval, out);
}